// Round 3
// baseline (541.395 us; speedup 1.0000x reference)
//
#include <hip/hip_runtime.h>

// LiquidTimeConstantCell fused kernel, MI355X gfx950 — R9.
// Same MFMA layout / math as R8 (transposed MFMA: C row = h, col = batch r,
// bf16 GEMM inputs, fp32 state).
// CHANGES vs R8 (attacking the 4-waves/SIMD occupancy cap at fixed grid):
//   1. 1024 threads / 16 waves per block, ROWS=64, grid=512 unchanged.
//      Wave = (rHalf, hTile): each wave owns 16 h-cols x 32 batch rows (NT=2).
//      -> 2 blocks/CU x 16 waves = 8 waves/SIMD (2x R8), per-wave stage chain
//      halves. Per-wave state ~56 regs -> __launch_bounds__(1024,8) (<=64 VGPR).
//   2. Everything else identical: double-buffered ldsY (1 barrier/stage),
//      deferred ode_out store under stage-1 feval, branchless tanh.

constexpr int kB   = 32768;
constexpr int kH   = 128;
constexpr int kIn  = 128;
constexpr int kT   = 10;
constexpr int ROWS = 64;     // batch rows per block -> 512 blocks (2/CU exactly)
constexpr int NT   = 2;      // row tiles per wave (32 rows)
constexpr int LDSW = 136;    // padded bf16 row stride
constexpr int HIN  = 256;    // H + IN

typedef __bf16 bf16;
typedef __attribute__((ext_vector_type(8))) __bf16 bf16x8;
typedef __attribute__((ext_vector_type(4))) __bf16 bf16x4;
typedef __attribute__((ext_vector_type(4))) float  f32x4;

__device__ __forceinline__ float sigmoid_(float v) {
  return __fdividef(1.0f, 1.0f + __expf(-v));
}
// tanh(v) = 1 - 2/(1 + e^{2v}); exact for all v (e=inf -> 1, e=0 -> -1), branchless.
__device__ __forceinline__ float tanh_(float v) {
  float e = __expf(2.0f * v);
  return 1.0f - __fdividef(2.0f, 1.0f + e);
}

__device__ __forceinline__ bf16x8 cvt8(const float* p) {
  float4 f0 = *(const float4*)p;
  float4 f1 = *(const float4*)(p + 4);
  bf16x8 t;
  t[0]=(bf16)f0.x; t[1]=(bf16)f0.y; t[2]=(bf16)f0.z; t[3]=(bf16)f0.w;
  t[4]=(bf16)f1.x; t[5]=(bf16)f1.y; t[6]=(bf16)f1.z; t[7]=(bf16)f1.w;
  return t;
}

// C[nt] += bf16(Wb[hrow][kofs+k]) * S[rbase + r][k];  hrow = hTile*16 + l16
// (A, m=l16), r = nt*16 + l16 (B, n=l16), k = kk*32 + quad*8 + j.
__device__ __forceinline__ void gemm4(
    f32x4 (&C)[NT], const bf16 (*S)[LDSW],
    const float* __restrict__ Wb, int ldw, int kofs,
    int hTile, int rbase, int quad, int l16)
{
#pragma unroll
  for (int kk = 0; kk < 4; ++kk) {
    bf16x8 af = cvt8(Wb + (size_t)(hTile*16 + l16) * ldw + kofs + kk*32 + quad*8);
#pragma unroll
    for (int nt = 0; nt < NT; ++nt) {
      bf16x8 bfv = *(const bf16x8*)&S[rbase + nt*16 + l16][kk*32 + quad*8];
      C[nt] = __builtin_amdgcn_mfma_f32_16x16x32_bf16(af, bfv, C[nt], 0, 0, 0);
    }
  }
}

// K = bias + Weff @ z^T, z read from Y (bf16)
__device__ __forceinline__ void feval(
    f32x4 (&K)[NT], const bf16x8 (&weff)[4], const bf16 (*Y)[LDSW],
    float4 bv, int rbase, int quad, int l16)
{
#pragma unroll
  for (int nt = 0; nt < NT; ++nt)
    K[nt] = f32x4{bv.x, bv.y, bv.z, bv.w};
#pragma unroll
  for (int kk = 0; kk < 4; ++kk)
#pragma unroll
    for (int nt = 0; nt < NT; ++nt) {
      bf16x8 bfv = *(const bf16x8*)&Y[rbase + nt*16 + l16][kk*32 + quad*8];
      K[nt] = __builtin_amdgcn_mfma_f32_16x16x32_bf16(weff[kk], bfv, K[nt], 0, 0, 0);
    }
}

// store V to LDS Y[rbase + r][h] as bf16 (LDS only)
__device__ __forceinline__ void storeTile(
    bf16 (*Y)[LDSW], const f32x4 (&V)[NT], int hc0, int rbase, int l16)
{
#pragma unroll
  for (int nt = 0; nt < NT; ++nt) {
    bf16x4 p;
    p[0]=(bf16)V[nt][0]; p[1]=(bf16)V[nt][1];
    p[2]=(bf16)V[nt][2]; p[3]=(bf16)V[nt][3];
    *(bf16x4*)&Y[rbase + nt*16 + l16][hc0] = p;
  }
}

// store V to global fp32, row-major [r][h], gbase pre-offset to block rows
__device__ __forceinline__ void storeGlob(
    float* gbase, const f32x4 (&V)[NT], int hc0, int rbase, int l16)
{
#pragma unroll
  for (int nt = 0; nt < NT; ++nt) {
    float4 g{V[nt][0], V[nt][1], V[nt][2], V[nt][3]};
    *(float4*)(gbase + (size_t)(rbase + nt*16 + l16) * kH + hc0) = g;
  }
}

__global__ __launch_bounds__(1024, 8) void ltc_kernel(
    const float* __restrict__ x,     const float* __restrict__ hidden,
    const float* __restrict__ ts,    const float* __restrict__ wiring,
    const float* __restrict__ W,     const float* __restrict__ bb_,
    const float* __restrict__ W_in,  const float* __restrict__ b_in,
    const float* __restrict__ W_upd, const float* __restrict__ b_upd,
    const float* __restrict__ W_rst, const float* __restrict__ b_rst,
    float* __restrict__ out)   // FP32 output: [new_hidden (B,H); ode_out (T,B,H)]
{
  __shared__ bf16 ldsX [ROWS][LDSW];   // x tile; later h0 (bf16)
  __shared__ bf16 ldsHd[ROWS][LDSW];   // hidden tile; later u (bf16)
  __shared__ bf16 ldsY0[ROWS][LDSW];   // ODE state z, ping
  __shared__ bf16 ldsY1[ROWS][LDSW];   // ODE state z, pong
  __shared__ float sts[kT];

  const int tid   = threadIdx.x;
  const int wave  = tid >> 6;          // 0..15
  const int hTile = wave & 7;          // h-column tile (16 cols)
  const int rbase = (wave >> 3) * 32;  // row half: 0 or 32
  const int lane  = tid & 63;
  const int quad  = lane >> 4;
  const int l16   = lane & 15;
  const int r0    = blockIdx.x * ROWS;

  if (tid < kT) sts[tid] = ts[tid];

  // ---- stage x & hidden tiles into LDS as bf16 (1024 threads, 64x32 float4) ----
#pragma unroll
  for (int i = 0; i < 2; ++i) {
    int idx = i*1024 + tid;           // float4 index in 64x32
    int row = idx >> 5;
    int c4  = (idx & 31) * 4;
    float4 vx = *(const float4*)(x      + (size_t)(r0+row)*kIn + c4);
    float4 vh = *(const float4*)(hidden + (size_t)(r0+row)*kH  + c4);
    bf16x4 bx; bx[0]=(bf16)vx.x; bx[1]=(bf16)vx.y; bx[2]=(bf16)vx.z; bx[3]=(bf16)vx.w;
    bf16x4 bh; bh[0]=(bf16)vh.x; bh[1]=(bf16)vh.y; bh[2]=(bf16)vh.z; bh[3]=(bf16)vh.w;
    *(bf16x4*)&ldsX [row][c4] = bx;
    *(bf16x4*)&ldsHd[row][c4] = bh;
  }

  const int hc0 = hTile*16 + quad*4;   // lane's C-tile h base (4 cols)

  // ---- persistent W_eff = W .* wiring, A-fragments (16 VGPRs) ----
  bf16x8 weff[4];
  {
    int hrow = hTile*16 + l16;
#pragma unroll
    for (int kk = 0; kk < 4; ++kk) {
      int k = kk*32 + quad*8;
      const float* wp = W      + (size_t)hrow*kH + k;
      const float* mp = wiring + (size_t)hrow*kH + k;
      float4 w0 = *(const float4*)wp, w1 = *(const float4*)(wp+4);
      float4 m0 = *(const float4*)mp, m1 = *(const float4*)(mp+4);
      bf16x8 t;
      t[0]=(bf16)(w0.x*m0.x); t[1]=(bf16)(w0.y*m0.y);
      t[2]=(bf16)(w0.z*m0.z); t[3]=(bf16)(w0.w*m0.w);
      t[4]=(bf16)(w1.x*m1.x); t[5]=(bf16)(w1.y*m1.y);
      t[6]=(bf16)(w1.z*m1.z); t[7]=(bf16)(w1.w*m1.w);
      weff[kk] = t;
    }
  }
  float4 bv = *(const float4*)(bb_ + hc0);

  __syncthreads();   // x/hidden tiles visible

  // ---- x_proj (persistent regs) ----
  f32x4 xp[NT];
  {
    float4 bi = *(const float4*)(b_in + hc0);
#pragma unroll
    for (int nt = 0; nt < NT; ++nt)
      xp[nt] = f32x4{bi.x, bi.y, bi.z, bi.w};
    gemm4(xp, ldsX, W_in, kIn, 0, hTile, rbase, quad, l16);
  }

  // ---- both gates up front ----
  f32x4 h[NT], U[NT];
  {
    f32x4 R[NT];
    float4 br = *(const float4*)(b_rst + hc0);
    float4 bu = *(const float4*)(b_upd + hc0);
#pragma unroll
    for (int nt = 0; nt < NT; ++nt) {
      R[nt] = f32x4{br.x, br.y, br.z, br.w};
      U[nt] = f32x4{bu.x, bu.y, bu.z, bu.w};
    }
    gemm4(R, ldsHd, W_rst, HIN, 0,  hTile, rbase, quad, l16);
    gemm4(R, ldsX,  W_rst, HIN, kH, hTile, rbase, quad, l16);
    gemm4(U, ldsHd, W_upd, HIN, 0,  hTile, rbase, quad, l16);
    gemm4(U, ldsX,  W_upd, HIN, kH, hTile, rbase, quad, l16);

#pragma unroll
    for (int nt = 0; nt < NT; ++nt) {
      const float* hp = hidden + (size_t)(r0 + rbase + nt*16 + l16)*kH + hc0;
      float4 hv = *(const float4*)hp;
      h[nt][0] = sigmoid_(R[nt][0]) * hv.x;   // h0
      h[nt][1] = sigmoid_(R[nt][1]) * hv.y;
      h[nt][2] = sigmoid_(R[nt][2]) * hv.z;
      h[nt][3] = sigmoid_(R[nt][3]) * hv.w;
      U[nt][0] = sigmoid_(U[nt][0]);          // u
      U[nt][1] = sigmoid_(U[nt][1]);
      U[nt][2] = sigmoid_(U[nt][2]);
      U[nt][3] = sigmoid_(U[nt][3]);
    }
  }

  __syncthreads();   // gate GEMM reads of ldsX/ldsHd done -> tiles reusable

  // park u and h0 in the now-dead tiles (bf16), freeing registers for the loop
  storeTile(ldsHd, U, hc0, rbase, l16);
  storeTile(ldsX,  h, hc0, rbase, l16);
  storeTile(ldsY0, h, hc0, rbase, l16);   // z = h0 (ping buffer)

  f32x4 z[NT], hacc[NT], K[NT];
#pragma unroll
  for (int nt = 0; nt < NT; ++nt) z[nt] = h[nt];

  float* odeBase = out + (size_t)kB*kH + (size_t)r0*kH;

  for (int t = 1; t < kT; ++t) {
    float dt  = sts[t] - sts[t-1];   // via LDS (R1: uniform global read ISel bug)
    float dt6 = dt * (1.0f/6.0f);
    float dt3 = dt * (1.0f/3.0f);
    float dth = 0.5f * dt;

    // ---- stage 1: read Y0, write Y1 ----
    __syncthreads();
    // deferred ode_out[t-1] = h_{t-1}: drains under this stage's feval+pointwise
    storeGlob(odeBase + (size_t)(t-1)*kB*kH, h, hc0, rbase, l16);
    feval(K, weff, ldsY0, bv, rbase, quad, l16);
#pragma unroll
    for (int nt = 0; nt < NT; ++nt)
#pragma unroll
      for (int i = 0; i < 4; ++i) {
        float kv = tanh_(K[nt][i]) + xp[nt][i] - z[nt][i];
        hacc[nt][i] = h[nt][i] + dt6 * kv;
        z[nt][i]    = h[nt][i] + dth * kv;
      }
    storeTile(ldsY1, z, hc0, rbase, l16);

    // ---- stage 2: read Y1, write Y0 ----
    __syncthreads();
    feval(K, weff, ldsY1, bv, rbase, quad, l16);
#pragma unroll
    for (int nt = 0; nt < NT; ++nt)
#pragma unroll
      for (int i = 0; i < 4; ++i) {
        float kv = tanh_(K[nt][i]) + xp[nt][i] - z[nt][i];
        hacc[nt][i] += dt3 * kv;
        z[nt][i]     = h[nt][i] + dth * kv;
      }
    storeTile(ldsY0, z, hc0, rbase, l16);

    // ---- stage 3: read Y0, write Y1 ----
    __syncthreads();
    feval(K, weff, ldsY0, bv, rbase, quad, l16);
#pragma unroll
    for (int nt = 0; nt < NT; ++nt)
#pragma unroll
      for (int i = 0; i < 4; ++i) {
        float kv = tanh_(K[nt][i]) + xp[nt][i] - z[nt][i];
        hacc[nt][i] += dt3 * kv;
        z[nt][i]     = h[nt][i] + dt * kv;
      }
    storeTile(ldsY1, z, hc0, rbase, l16);

    // ---- stage 4: read Y1, write Y0 ----
    __syncthreads();
    feval(K, weff, ldsY1, bv, rbase, quad, l16);
#pragma unroll
    for (int nt = 0; nt < NT; ++nt)
#pragma unroll
      for (int i = 0; i < 4; ++i) {
        float kv = tanh_(K[nt][i]) + xp[nt][i] - z[nt][i];
        h[nt][i] = hacc[nt][i] + dt6 * kv;
        z[nt][i] = h[nt][i];
      }
    storeTile(ldsY0, z, hc0, rbase, l16);   // next step's stage 1 reads Y0
  }

  // last ode slab: ode_out[T-1] = h_last
  storeGlob(odeBase + (size_t)(kT-1)*kB*kH, h, hc0, rbase, l16);

  // ---- final blend: new_hidden = u*h_last + (1-u)*h0 (fp32 store) ----
  // parked u/h0 rectangles were written by this same wave -> no barrier needed
#pragma unroll
  for (int nt = 0; nt < NT; ++nt) {
    int r = rbase + nt*16 + l16;
    bf16x4 uv  = *(const bf16x4*)&ldsHd[r][hc0];
    bf16x4 h0v = *(const bf16x4*)&ldsX [r][hc0];
    float4 p;
    {
      float uu;
      uu = (float)uv[0]; p.x = uu * h[nt][0] + (1.0f - uu) * (float)h0v[0];
      uu = (float)uv[1]; p.y = uu * h[nt][1] + (1.0f - uu) * (float)h0v[1];
      uu = (float)uv[2]; p.z = uu * h[nt][2] + (1.0f - uu) * (float)h0v[2];
      uu = (float)uv[3]; p.w = uu * h[nt][3] + (1.0f - uu) * (float)h0v[3];
    }
    *(float4*)(out + (size_t)(r0 + r) * kH + hc0) = p;
  }
}

extern "C" void kernel_launch(void* const* d_in, const int* in_sizes, int n_in,
                              void* d_out, int out_size, void* d_ws, size_t ws_size,
                              hipStream_t stream) {
  (void)d_ws; (void)ws_size; (void)out_size;
  // Resolve input order from in_sizes (insurance; documented order expected).
  int ix=0, ih=1, its=2, iwr=3, iW=4, ib=5, iWin=6, ibin=7, iWu=8, ibu=9, iWr=10, ibr=11;
  if (n_in == 12 && in_sizes[2] != 10 && in_sizes[5] == 10) {
    // case-insensitive name-sorted: b,b_in,b_rst,b_upd,hidden,time_span,W,W_in,W_rst,W_upd,wiring,x
    ib=0; ibin=1; ibr=2; ibu=3; ih=4; its=5; iW=6; iWin=7; iWr=8; iWu=9; iwr=10; ix=11;
  }
  const float* x      = (const float*)d_in[ix];
  const float* hidden = (const float*)d_in[ih];
  const float* ts     = (const float*)d_in[its];
  const float* wiring = (const float*)d_in[iwr];
  const float* W      = (const float*)d_in[iW];
  const float* b      = (const float*)d_in[ib];
  const float* W_in   = (const float*)d_in[iWin];
  const float* b_in   = (const float*)d_in[ibin];
  const float* W_upd  = (const float*)d_in[iWu];
  const float* b_upd  = (const float*)d_in[ibu];
  const float* W_rst  = (const float*)d_in[iWr];
  const float* b_rst  = (const float*)d_in[ibr];

  dim3 grid(kB / ROWS);   // 512 blocks -> 2 blocks/CU, 16 waves each
  dim3 block(1024);
  ltc_kernel<<<grid, block, 0, stream>>>(x, hidden, ts, wiring, W, b,
                                         W_in, b_in, W_upd, b_upd, W_rst, b_rst,
                                         (float*)d_out);
}

// Round 4
// 348.576 us; speedup vs baseline: 1.5532x; 1.5532x over previous
//
#include <hip/hip_runtime.h>

// LiquidTimeConstantCell fused kernel, MI355X gfx950 — R10.
// Same MFMA layout / math as R8/R9 (transposed MFMA: C row = h, col = batch r,
// bf16 GEMM inputs, fp32 state).
// CHANGE vs R9 (fixing the spill cliff): __launch_bounds__(1024, 8) -> (1024, 4).
// R9's (1024,8) made the compiler clamp to 32 VGPRs -> ~56-reg loop state
// spilled to scratch (FETCH 52->575MB, WRITE 228->734MB, VALUBusy 25%).
// Empirical hipcc rule on this kernel family: grantedVGPR ~= 256/arg2
// ((512,4)->64, (1024,8)->32). (1024,4) -> 64 VGPR, which held R8's DOUBLE
// state (NT=4) spill-free. Residency is resource-determined, not arg2-capped:
// LDS 70KB -> 2 blocks/CU, VGPR 64 -> 8 waves/SIMD => 32 waves/CU (R9 proved
// the residency: 81% occupancy), now without spill traffic.

constexpr int kB   = 32768;
constexpr int kH   = 128;
constexpr int kIn  = 128;
constexpr int kT   = 10;
constexpr int ROWS = 64;     // batch rows per block -> 512 blocks (2/CU exactly)
constexpr int NT   = 2;      // row tiles per wave (32 rows)
constexpr int LDSW = 136;    // padded bf16 row stride
constexpr int HIN  = 256;    // H + IN

typedef __bf16 bf16;
typedef __attribute__((ext_vector_type(8))) __bf16 bf16x8;
typedef __attribute__((ext_vector_type(4))) __bf16 bf16x4;
typedef __attribute__((ext_vector_type(4))) float  f32x4;

__device__ __forceinline__ float sigmoid_(float v) {
  return __fdividef(1.0f, 1.0f + __expf(-v));
}
// tanh(v) = 1 - 2/(1 + e^{2v}); exact for all v (e=inf -> 1, e=0 -> -1), branchless.
__device__ __forceinline__ float tanh_(float v) {
  float e = __expf(2.0f * v);
  return 1.0f - __fdividef(2.0f, 1.0f + e);
}

__device__ __forceinline__ bf16x8 cvt8(const float* p) {
  float4 f0 = *(const float4*)p;
  float4 f1 = *(const float4*)(p + 4);
  bf16x8 t;
  t[0]=(bf16)f0.x; t[1]=(bf16)f0.y; t[2]=(bf16)f0.z; t[3]=(bf16)f0.w;
  t[4]=(bf16)f1.x; t[5]=(bf16)f1.y; t[6]=(bf16)f1.z; t[7]=(bf16)f1.w;
  return t;
}

// C[nt] += bf16(Wb[hrow][kofs+k]) * S[rbase + r][k];  hrow = hTile*16 + l16
// (A, m=l16), r = nt*16 + l16 (B, n=l16), k = kk*32 + quad*8 + j.
__device__ __forceinline__ void gemm4(
    f32x4 (&C)[NT], const bf16 (*S)[LDSW],
    const float* __restrict__ Wb, int ldw, int kofs,
    int hTile, int rbase, int quad, int l16)
{
#pragma unroll
  for (int kk = 0; kk < 4; ++kk) {
    bf16x8 af = cvt8(Wb + (size_t)(hTile*16 + l16) * ldw + kofs + kk*32 + quad*8);
#pragma unroll
    for (int nt = 0; nt < NT; ++nt) {
      bf16x8 bfv = *(const bf16x8*)&S[rbase + nt*16 + l16][kk*32 + quad*8];
      C[nt] = __builtin_amdgcn_mfma_f32_16x16x32_bf16(af, bfv, C[nt], 0, 0, 0);
    }
  }
}

// K = bias + Weff @ z^T, z read from Y (bf16)
__device__ __forceinline__ void feval(
    f32x4 (&K)[NT], const bf16x8 (&weff)[4], const bf16 (*Y)[LDSW],
    float4 bv, int rbase, int quad, int l16)
{
#pragma unroll
  for (int nt = 0; nt < NT; ++nt)
    K[nt] = f32x4{bv.x, bv.y, bv.z, bv.w};
#pragma unroll
  for (int kk = 0; kk < 4; ++kk)
#pragma unroll
    for (int nt = 0; nt < NT; ++nt) {
      bf16x8 bfv = *(const bf16x8*)&Y[rbase + nt*16 + l16][kk*32 + quad*8];
      K[nt] = __builtin_amdgcn_mfma_f32_16x16x32_bf16(weff[kk], bfv, K[nt], 0, 0, 0);
    }
}

// store V to LDS Y[rbase + r][h] as bf16 (LDS only)
__device__ __forceinline__ void storeTile(
    bf16 (*Y)[LDSW], const f32x4 (&V)[NT], int hc0, int rbase, int l16)
{
#pragma unroll
  for (int nt = 0; nt < NT; ++nt) {
    bf16x4 p;
    p[0]=(bf16)V[nt][0]; p[1]=(bf16)V[nt][1];
    p[2]=(bf16)V[nt][2]; p[3]=(bf16)V[nt][3];
    *(bf16x4*)&Y[rbase + nt*16 + l16][hc0] = p;
  }
}

// store V to global fp32, row-major [r][h], gbase pre-offset to block rows
__device__ __forceinline__ void storeGlob(
    float* gbase, const f32x4 (&V)[NT], int hc0, int rbase, int l16)
{
#pragma unroll
  for (int nt = 0; nt < NT; ++nt) {
    float4 g{V[nt][0], V[nt][1], V[nt][2], V[nt][3]};
    *(float4*)(gbase + (size_t)(rbase + nt*16 + l16) * kH + hc0) = g;
  }
}

__global__ __launch_bounds__(1024, 4) void ltc_kernel(
    const float* __restrict__ x,     const float* __restrict__ hidden,
    const float* __restrict__ ts,    const float* __restrict__ wiring,
    const float* __restrict__ W,     const float* __restrict__ bb_,
    const float* __restrict__ W_in,  const float* __restrict__ b_in,
    const float* __restrict__ W_upd, const float* __restrict__ b_upd,
    const float* __restrict__ W_rst, const float* __restrict__ b_rst,
    float* __restrict__ out)   // FP32 output: [new_hidden (B,H); ode_out (T,B,H)]
{
  __shared__ bf16 ldsX [ROWS][LDSW];   // x tile; later h0 (bf16)
  __shared__ bf16 ldsHd[ROWS][LDSW];   // hidden tile; later u (bf16)
  __shared__ bf16 ldsY0[ROWS][LDSW];   // ODE state z, ping
  __shared__ bf16 ldsY1[ROWS][LDSW];   // ODE state z, pong
  __shared__ float sts[kT];

  const int tid   = threadIdx.x;
  const int wave  = tid >> 6;          // 0..15
  const int hTile = wave & 7;          // h-column tile (16 cols)
  const int rbase = (wave >> 3) * 32;  // row half: 0 or 32
  const int lane  = tid & 63;
  const int quad  = lane >> 4;
  const int l16   = lane & 15;
  const int r0    = blockIdx.x * ROWS;

  if (tid < kT) sts[tid] = ts[tid];

  // ---- stage x & hidden tiles into LDS as bf16 (1024 threads, 64x32 float4) ----
#pragma unroll
  for (int i = 0; i < 2; ++i) {
    int idx = i*1024 + tid;           // float4 index in 64x32
    int row = idx >> 5;
    int c4  = (idx & 31) * 4;
    float4 vx = *(const float4*)(x      + (size_t)(r0+row)*kIn + c4);
    float4 vh = *(const float4*)(hidden + (size_t)(r0+row)*kH  + c4);
    bf16x4 bx; bx[0]=(bf16)vx.x; bx[1]=(bf16)vx.y; bx[2]=(bf16)vx.z; bx[3]=(bf16)vx.w;
    bf16x4 bh; bh[0]=(bf16)vh.x; bh[1]=(bf16)vh.y; bh[2]=(bf16)vh.z; bh[3]=(bf16)vh.w;
    *(bf16x4*)&ldsX [row][c4] = bx;
    *(bf16x4*)&ldsHd[row][c4] = bh;
  }

  const int hc0 = hTile*16 + quad*4;   // lane's C-tile h base (4 cols)

  // ---- persistent W_eff = W .* wiring, A-fragments (16 VGPRs) ----
  bf16x8 weff[4];
  {
    int hrow = hTile*16 + l16;
#pragma unroll
    for (int kk = 0; kk < 4; ++kk) {
      int k = kk*32 + quad*8;
      const float* wp = W      + (size_t)hrow*kH + k;
      const float* mp = wiring + (size_t)hrow*kH + k;
      float4 w0 = *(const float4*)wp, w1 = *(const float4*)(wp+4);
      float4 m0 = *(const float4*)mp, m1 = *(const float4*)(mp+4);
      bf16x8 t;
      t[0]=(bf16)(w0.x*m0.x); t[1]=(bf16)(w0.y*m0.y);
      t[2]=(bf16)(w0.z*m0.z); t[3]=(bf16)(w0.w*m0.w);
      t[4]=(bf16)(w1.x*m1.x); t[5]=(bf16)(w1.y*m1.y);
      t[6]=(bf16)(w1.z*m1.z); t[7]=(bf16)(w1.w*m1.w);
      weff[kk] = t;
    }
  }
  float4 bv = *(const float4*)(bb_ + hc0);

  __syncthreads();   // x/hidden tiles visible

  // ---- x_proj (persistent regs) ----
  f32x4 xp[NT];
  {
    float4 bi = *(const float4*)(b_in + hc0);
#pragma unroll
    for (int nt = 0; nt < NT; ++nt)
      xp[nt] = f32x4{bi.x, bi.y, bi.z, bi.w};
    gemm4(xp, ldsX, W_in, kIn, 0, hTile, rbase, quad, l16);
  }

  // ---- both gates up front ----
  f32x4 h[NT], U[NT];
  {
    f32x4 R[NT];
    float4 br = *(const float4*)(b_rst + hc0);
    float4 bu = *(const float4*)(b_upd + hc0);
#pragma unroll
    for (int nt = 0; nt < NT; ++nt) {
      R[nt] = f32x4{br.x, br.y, br.z, br.w};
      U[nt] = f32x4{bu.x, bu.y, bu.z, bu.w};
    }
    gemm4(R, ldsHd, W_rst, HIN, 0,  hTile, rbase, quad, l16);
    gemm4(R, ldsX,  W_rst, HIN, kH, hTile, rbase, quad, l16);
    gemm4(U, ldsHd, W_upd, HIN, 0,  hTile, rbase, quad, l16);
    gemm4(U, ldsX,  W_upd, HIN, kH, hTile, rbase, quad, l16);

#pragma unroll
    for (int nt = 0; nt < NT; ++nt) {
      const float* hp = hidden + (size_t)(r0 + rbase + nt*16 + l16)*kH + hc0;
      float4 hv = *(const float4*)hp;
      h[nt][0] = sigmoid_(R[nt][0]) * hv.x;   // h0
      h[nt][1] = sigmoid_(R[nt][1]) * hv.y;
      h[nt][2] = sigmoid_(R[nt][2]) * hv.z;
      h[nt][3] = sigmoid_(R[nt][3]) * hv.w;
      U[nt][0] = sigmoid_(U[nt][0]);          // u
      U[nt][1] = sigmoid_(U[nt][1]);
      U[nt][2] = sigmoid_(U[nt][2]);
      U[nt][3] = sigmoid_(U[nt][3]);
    }
  }

  __syncthreads();   // gate GEMM reads of ldsX/ldsHd done -> tiles reusable

  // park u and h0 in the now-dead tiles (bf16), freeing registers for the loop
  storeTile(ldsHd, U, hc0, rbase, l16);
  storeTile(ldsX,  h, hc0, rbase, l16);
  storeTile(ldsY0, h, hc0, rbase, l16);   // z = h0 (ping buffer)

  f32x4 z[NT], hacc[NT], K[NT];
#pragma unroll
  for (int nt = 0; nt < NT; ++nt) z[nt] = h[nt];

  float* odeBase = out + (size_t)kB*kH + (size_t)r0*kH;

  for (int t = 1; t < kT; ++t) {
    float dt  = sts[t] - sts[t-1];   // via LDS (R1: uniform global read ISel bug)
    float dt6 = dt * (1.0f/6.0f);
    float dt3 = dt * (1.0f/3.0f);
    float dth = 0.5f * dt;

    // ---- stage 1: read Y0, write Y1 ----
    __syncthreads();
    // deferred ode_out[t-1] = h_{t-1}: drains under this stage's feval+pointwise
    storeGlob(odeBase + (size_t)(t-1)*kB*kH, h, hc0, rbase, l16);
    feval(K, weff, ldsY0, bv, rbase, quad, l16);
#pragma unroll
    for (int nt = 0; nt < NT; ++nt)
#pragma unroll
      for (int i = 0; i < 4; ++i) {
        float kv = tanh_(K[nt][i]) + xp[nt][i] - z[nt][i];
        hacc[nt][i] = h[nt][i] + dt6 * kv;
        z[nt][i]    = h[nt][i] + dth * kv;
      }
    storeTile(ldsY1, z, hc0, rbase, l16);

    // ---- stage 2: read Y1, write Y0 ----
    __syncthreads();
    feval(K, weff, ldsY1, bv, rbase, quad, l16);
#pragma unroll
    for (int nt = 0; nt < NT; ++nt)
#pragma unroll
      for (int i = 0; i < 4; ++i) {
        float kv = tanh_(K[nt][i]) + xp[nt][i] - z[nt][i];
        hacc[nt][i] += dt3 * kv;
        z[nt][i]     = h[nt][i] + dth * kv;
      }
    storeTile(ldsY0, z, hc0, rbase, l16);

    // ---- stage 3: read Y0, write Y1 ----
    __syncthreads();
    feval(K, weff, ldsY0, bv, rbase, quad, l16);
#pragma unroll
    for (int nt = 0; nt < NT; ++nt)
#pragma unroll
      for (int i = 0; i < 4; ++i) {
        float kv = tanh_(K[nt][i]) + xp[nt][i] - z[nt][i];
        hacc[nt][i] += dt3 * kv;
        z[nt][i]     = h[nt][i] + dt * kv;
      }
    storeTile(ldsY1, z, hc0, rbase, l16);

    // ---- stage 4: read Y1, write Y0 ----
    __syncthreads();
    feval(K, weff, ldsY1, bv, rbase, quad, l16);
#pragma unroll
    for (int nt = 0; nt < NT; ++nt)
#pragma unroll
      for (int i = 0; i < 4; ++i) {
        float kv = tanh_(K[nt][i]) + xp[nt][i] - z[nt][i];
        h[nt][i] = hacc[nt][i] + dt6 * kv;
        z[nt][i] = h[nt][i];
      }
    storeTile(ldsY0, z, hc0, rbase, l16);   // next step's stage 1 reads Y0
  }

  // last ode slab: ode_out[T-1] = h_last
  storeGlob(odeBase + (size_t)(kT-1)*kB*kH, h, hc0, rbase, l16);

  // ---- final blend: new_hidden = u*h_last + (1-u)*h0 (fp32 store) ----
  // parked u/h0 rectangles were written by this same wave -> no barrier needed
#pragma unroll
  for (int nt = 0; nt < NT; ++nt) {
    int r = rbase + nt*16 + l16;
    bf16x4 uv  = *(const bf16x4*)&ldsHd[r][hc0];
    bf16x4 h0v = *(const bf16x4*)&ldsX [r][hc0];
    float4 p;
    {
      float uu;
      uu = (float)uv[0]; p.x = uu * h[nt][0] + (1.0f - uu) * (float)h0v[0];
      uu = (float)uv[1]; p.y = uu * h[nt][1] + (1.0f - uu) * (float)h0v[1];
      uu = (float)uv[2]; p.z = uu * h[nt][2] + (1.0f - uu) * (float)h0v[2];
      uu = (float)uv[3]; p.w = uu * h[nt][3] + (1.0f - uu) * (float)h0v[3];
    }
    *(float4*)(out + (size_t)(r0 + r) * kH + hc0) = p;
  }
}

extern "C" void kernel_launch(void* const* d_in, const int* in_sizes, int n_in,
                              void* d_out, int out_size, void* d_ws, size_t ws_size,
                              hipStream_t stream) {
  (void)d_ws; (void)ws_size; (void)out_size;
  // Resolve input order from in_sizes (insurance; documented order expected).
  int ix=0, ih=1, its=2, iwr=3, iW=4, ib=5, iWin=6, ibin=7, iWu=8, ibu=9, iWr=10, ibr=11;
  if (n_in == 12 && in_sizes[2] != 10 && in_sizes[5] == 10) {
    // case-insensitive name-sorted: b,b_in,b_rst,b_upd,hidden,time_span,W,W_in,W_rst,W_upd,wiring,x
    ib=0; ibin=1; ibr=2; ibu=3; ih=4; its=5; iW=6; iWin=7; iWr=8; iWu=9; iwr=10; ix=11;
  }
  const float* x      = (const float*)d_in[ix];
  const float* hidden = (const float*)d_in[ih];
  const float* ts     = (const float*)d_in[its];
  const float* wiring = (const float*)d_in[iwr];
  const float* W      = (const float*)d_in[iW];
  const float* b      = (const float*)d_in[ib];
  const float* W_in   = (const float*)d_in[iWin];
  const float* b_in   = (const float*)d_in[ibin];
  const float* W_upd  = (const float*)d_in[iWu];
  const float* b_upd  = (const float*)d_in[ibu];
  const float* W_rst  = (const float*)d_in[iWr];
  const float* b_rst  = (const float*)d_in[ibr];

  dim3 grid(kB / ROWS);   // 512 blocks -> 2 blocks/CU, 16 waves each
  dim3 block(1024);
  ltc_kernel<<<grid, block, 0, stream>>>(x, hidden, ts, wiring, W, b,
                                         W_in, b_in, W_upd, b_upd, W_rst, b_rst,
                                         (float*)d_out);
}